// Round 6
// baseline (300.960 us; speedup 1.0000x reference)
//
#include <hip/hip_runtime.h>
#include <hip/hip_bf16.h>

// IWHT3Layer: 3 branches of (per-coeff matmul [16,12544,64]x[16,64,64]) +
// inverse 2D 4x4 WHT over the 16 coefficients + bias.
// Inputs: float32. Output: float32.
//
// R10 change vs R9 (100us; 5 schedule variants all ~100-112us, all pipes
// idle): counters show 2 blocks/CU * 2352 blocks = 4.6 sequential
// GENERATIONS, block lifetime 52k cyc vs ~2k cyc of real work -> the kernel
// is convoys of cold-start latency ramps + store drains. Fix: PERSISTENT
// blocks. 512 blocks (exactly 2/CU, ONE generation), each owns 4-5
// consecutive tiles of a single branch (171/171/170 split -> wf/bias loaded
// once per block). Ring-4 chunk buffers (chunk g of any tile -> buf g,
// 64KB LDS). Per phase g of tile t: vmcnt(counted) -> barrier -> COMPUTE(g)
// -> barrier -> STAGE(t+1,g); stores of tile t issue in phase 3 BEHIND 3
// staged chunks of tile t+1 -> loads always behind stores, pipe never cold.
// In-order vmcnt bookkeeping (m135): steady state = 12 loads + 16 stores in
// flight, wait literal vmcnt(28) every phase; first tile 12; last tile
// 28/24/20/16. All VMEM issue points pinned with sched_barrier(0).
// Compute / LDS swizzle / MFMA operands / WHT / epilogue byte-identical to
// verified R9.

typedef __attribute__((ext_vector_type(8))) short bf16x8;   // 8 bf16 (4 VGPRs)
typedef __attribute__((ext_vector_type(4))) float floatx4;  // MFMA C/D

#define NSITES 12544
#define NTILES 784
#define OUT_PER_BRANCH 12845056  // 16*112*112*64
#define WT_ELEMS (3*16*64*64)
#define CHUNK_F (64 * 64)        // 4 t * 16 rows * 64 floats = 16384 B per chunk
#define NBLOCKS 512

__device__ __forceinline__ short f32_to_bf16_bits(float f) {
    __hip_bfloat16 h = __float2bfloat16(f);  // RNE
    return *reinterpret_cast<short*>(&h);
}

__global__ void transpose_weights(const float* __restrict__ w0,
                                  const float* __restrict__ w1,
                                  const float* __restrict__ w2,
                                  __hip_bfloat16* __restrict__ wT) {
    int idx = blockIdx.x * blockDim.x + threadIdx.x;  // [0, 3*16*64*64)
    if (idx >= WT_ELEMS) return;
    int c  = idx & 63;
    int k  = (idx >> 6) & 63;
    int t  = (idx >> 12) & 15;
    int br = idx >> 16;
    const float* w = (br == 0) ? w0 : ((br == 1) ? w1 : w2);
    // wT[br][t][k][c] = bf16(w[br][t][c][k])
    wT[idx] = __float2bfloat16(w[(t * 64 + c) * 64 + k]);
}

template <bool USE_WT>
__global__ __launch_bounds__(256, 2) void iwht_kernel(
    const float* __restrict__ x0, const float* __restrict__ x1,
    const float* __restrict__ x2,
    const float* __restrict__ w0, const float* __restrict__ w1,
    const float* __restrict__ w2,
    const __hip_bfloat16* __restrict__ wT,
    const float* __restrict__ b0, const float* __restrict__ b1,
    const float* __restrict__ b2,
    float* __restrict__ out) {
    __shared__ float xs[4][CHUNK_F];  // 4 x 16384 B = 65536 B

    int bx   = blockIdx.x;
    int lane = threadIdx.x & 63;
    int wave = threadIdx.x >> 6;
    int l15  = lane & 15;
    int quad = lane >> 4;
    int n    = wave * 16 + l15;  // weight-fragment row: output channel block

    // Persistent-block work split: no block crosses a branch boundary.
    int br, bi, nb;
    if (bx < 171)      { br = 0; bi = bx;       nb = 171; }
    else if (bx < 342) { br = 1; bi = bx - 171; nb = 171; }
    else               { br = 2; bi = bx - 342; nb = 170; }
    int t0 = (bi * NTILES) / nb;
    int t1 = ((bi + 1) * NTILES) / nb;  // 4..5 tiles per block

    const float* x    = (br == 0) ? x0 : ((br == 1) ? x1 : x2);
    const float* w    = (br == 0) ? w0 : ((br == 1) ? w1 : w2);
    const float* bias = (br == 0) ? b0 : ((br == 1) ? b1 : b2);
    float* outb = out + (size_t)br * OUT_PER_BRANCH;

    // Width-16 DMA lane decomposition: inst covers 4 site-rows (1KB);
    // lane serves sub-row (lane>>4), 16B column (lane&15), XOR-swizzled
    // source so the linear LDS dest ends up swizzle-stored (rule #21).
    int sub  = lane >> 4;   // 0..3: which of the 4 rows in this inst
    int lcol = lane & 15;   // 16B column within the 256B row
    int rowoff[4];
#pragma unroll
    for (int r = 0; r < 4; r++) {
        int s = 4 * r + sub;
        rowoff[r] = s * 64 + ((lcol ^ (s & 7)) << 2);  // floats
    }

    int k0 = wave * 16 + quad * 4;

    floatx4 acc[16];
#pragma unroll
    for (int t = 0; t < 16; t++) acc[t] = (floatx4){0.f, 0.f, 0.f, 0.f};

    // --- bias + ALL weight fragments into registers, issued BEFORE any DMA
    // so the ring's counted vmcnt waits cover them (in-order completion). ---
    floatx4 bias4 = *reinterpret_cast<const floatx4*>(bias + k0);
    bf16x8 wf[32];
    if (USE_WT) {
#pragma unroll
        for (int t = 0; t < 16; t++) {
            const bf16x8* wv = reinterpret_cast<const bf16x8*>(
                wT + (((size_t)(br * 16 + t) * 64 + n) * 64) + quad * 8);
            wf[2 * t]     = wv[0];
            wf[2 * t + 1] = wv[4];  // +32 c elements
        }
    } else {
#pragma unroll
        for (int t = 0; t < 16; t++) {
#pragma unroll
            for (int j = 0; j < 8; j++) {
                int c0 = quad * 8 + j;
                wf[2 * t][j]     = f32_to_bf16_bits(w[(t * 64 + c0) * 64 + n]);
                wf[2 * t + 1][j] = f32_to_bf16_bits(w[(t * 64 + c0 + 32) * 64 + n]);
            }
        }
    }
    __builtin_amdgcn_sched_barrier(0);  // pin bias+wf loads before the DMAs

    // --- stage chunk g (t-planes 4g..4g+3) of tile tt into xs[g] ---
    // Wave w stages t-plane (4g + w): 16 site-rows as 4 width-16 DMAs,
    // source XOR-pre-swizzled, LDS dest linear.
#define STAGE(tt, g)                                                           \
    {                                                                          \
        _Pragma("unroll") for (int r = 0; r < 4; r++) {                        \
            const float* gp = x +                                              \
                (size_t)((g) * 4 + wave) * (NSITES * 64) +                     \
                (size_t)(tt) * 1024 + rowoff[r];                               \
            __builtin_amdgcn_global_load_lds(                                  \
                (const __attribute__((address_space(1))) void*)gp,             \
                (__attribute__((address_space(3))) void*)                      \
                    &xs[g][(wave * 16 + 4 * r) * 64],                          \
                16, 0, 0);                                                     \
        }                                                                      \
        __builtin_amdgcn_sched_barrier(0);                                     \
    }

    // --- compute chunk g from xs[g]: 4 t-planes, 2 MFMA each; weights from
    // wf registers -> ZERO VMEM. Read with the store-side XOR. ---
#define COMPUTE(g)                                                             \
    {                                                                          \
        int xr7 = l15 & 7;                                                     \
        _Pragma("unroll") for (int tl = 0; tl < 4; tl++) {                     \
            int t = (g) * 4 + tl;                                              \
            const float* rp = &xs[g][(tl * 16 + l15) * 64];                    \
            floatx4 f0 = *(const floatx4*)(rp + ((quad * 2) ^ xr7) * 4);       \
            floatx4 f1 = *(const floatx4*)(rp + ((quad * 2 + 1) ^ xr7) * 4);   \
            floatx4 f2 = *(const floatx4*)(rp + (((quad * 2) ^ xr7) + 8) * 4); \
            floatx4 f3 = *(const floatx4*)(rp + (((quad * 2 + 1) ^ xr7) + 8) * 4); \
            bf16x8 a0, a1;                                                     \
            _Pragma("unroll") for (int j = 0; j < 4; j++) {                    \
                a0[j]     = f32_to_bf16_bits(f0[j]);                           \
                a0[j + 4] = f32_to_bf16_bits(f1[j]);                           \
                a1[j]     = f32_to_bf16_bits(f2[j]);                           \
                a1[j + 4] = f32_to_bf16_bits(f3[j]);                           \
            }                                                                  \
            acc[t] = __builtin_amdgcn_mfma_f32_16x16x32_bf16(wf[2 * t], a0,    \
                                                             acc[t], 0, 0, 0); \
            acc[t] = __builtin_amdgcn_mfma_f32_16x16x32_bf16(wf[2 * t + 1], a1,\
                                                             acc[t], 0, 0, 0); \
        }                                                                      \
    }

    // --- WHT + bias + 16 dwordx4 stores for tile tt, then re-zero acc ---
#define STORES(tt)                                                             \
    {                                                                          \
        int site = (tt) * 16 + l15;                                            \
        int bb   = site / 784;                                                 \
        int rem  = site - bb * 784;                                            \
        int ii   = rem / 28;                                                   \
        int jj   = rem - ii * 28;                                              \
        float* op = outb +                                                     \
            (((size_t)(bb * 112 + 4 * ii)) * 112 + 4 * jj) * 64 + k0;          \
        _Pragma("unroll") for (int u = 0; u < 4; u++) {                        \
            floatx4 y0 = acc[4 * u + 0], y1 = acc[4 * u + 1];                  \
            floatx4 y2 = acc[4 * u + 2], y3 = acc[4 * u + 3];                  \
            floatx4 A = y0 + y2, Bv = y1 + y3, Cv = y0 - y2, Dv = y1 - y3;     \
            acc[4 * u + 0] = A + Bv;                                           \
            acc[4 * u + 1] = A - Bv;                                           \
            acc[4 * u + 2] = Cv + Dv;                                          \
            acc[4 * u + 3] = Cv - Dv;                                          \
        }                                                                      \
        _Pragma("unroll") for (int q = 0; q < 4; q++) {                        \
            floatx4 z0 = acc[0 + q], z1 = acc[4 + q];                          \
            floatx4 z2 = acc[8 + q], z3 = acc[12 + q];                         \
            floatx4 A = z0 + z2, Bv = z1 + z3, Cv = z0 - z2, Dv = z1 - z3;     \
            floatx4 o[4];                                                      \
            o[0] = A + Bv;                                                     \
            o[1] = A - Bv;                                                     \
            o[2] = Cv + Dv;                                                    \
            o[3] = Cv - Dv;                                                    \
            _Pragma("unroll") for (int p = 0; p < 4; p++) {                    \
                floatx4 v = o[p] * 0.0625f + bias4;                            \
                *reinterpret_cast<floatx4*>(op + (size_t)(p * 112 + q) * 64) = v; \
            }                                                                  \
        }                                                                      \
        _Pragma("unroll") for (int t = 0; t < 16; t++)                         \
            acc[t] = (floatx4){0.f, 0.f, 0.f, 0.f};                            \
        __builtin_amdgcn_sched_barrier(0);                                     \
    }

#define WAITV(N)                                                               \
    asm volatile("s_waitcnt vmcnt(" #N ")" ::: "memory");                      \
    __builtin_amdgcn_s_barrier();                                              \
    __builtin_amdgcn_sched_barrier(0);

#define BARSB                                                                  \
    __builtin_amdgcn_s_barrier();                                              \
    __builtin_amdgcn_sched_barrier(0);

    // Prologue: all 4 chunks of the first tile in flight (16 DMAs/wave).
    STAGE(t0, 0);
    STAGE(t0, 1);
    STAGE(t0, 2);
    STAGE(t0, 3);

    // ---- first tile (no prior stores): newer-than-target = 12 each phase ----
    WAITV(12); COMPUTE(0); BARSB; STAGE(t0 + 1, 0);
    WAITV(12); COMPUTE(1); BARSB; STAGE(t0 + 1, 1);
    WAITV(12); COMPUTE(2); BARSB; STAGE(t0 + 1, 2);
    WAITV(12); COMPUTE(3); BARSB; STAGE(t0 + 1, 3); STORES(t0);

    // ---- middle tiles: steady state = 12 loads + 16 stores in flight ----
    for (int tt = t0 + 1; tt <= t1 - 2; ++tt) {
        WAITV(28); COMPUTE(0); BARSB; STAGE(tt + 1, 0);
        WAITV(28); COMPUTE(1); BARSB; STAGE(tt + 1, 1);
        WAITV(28); COMPUTE(2); BARSB; STAGE(tt + 1, 2);
        WAITV(28); COMPUTE(3); BARSB; STAGE(tt + 1, 3); STORES(tt);
    }

    // ---- last tile: no staging; drain 28/24/20/16 ----
    WAITV(28); COMPUTE(0);
    WAITV(24); COMPUTE(1);
    WAITV(20); COMPUTE(2);
    WAITV(16); COMPUTE(3); STORES(t1 - 1);

#undef STAGE
#undef COMPUTE
#undef STORES
#undef WAITV
#undef BARSB
}

extern "C" void kernel_launch(void* const* d_in, const int* in_sizes, int n_in,
                              void* d_out, int out_size, void* d_ws, size_t ws_size,
                              hipStream_t stream) {
    const float* x0 = (const float*)d_in[0];
    const float* x1 = (const float*)d_in[1];
    const float* x2 = (const float*)d_in[2];
    const float* w0 = (const float*)d_in[3];
    const float* w1 = (const float*)d_in[4];
    const float* w2 = (const float*)d_in[5];
    const float* b0 = (const float*)d_in[6];
    const float* b1 = (const float*)d_in[7];
    const float* b2 = (const float*)d_in[8];
    float* out = (float*)d_out;
    __hip_bfloat16* wT = (__hip_bfloat16*)d_ws;

    bool use_wt = ws_size >= (size_t)WT_ELEMS * sizeof(__hip_bfloat16);
    if (use_wt) {
        transpose_weights<<<(WT_ELEMS + 255) / 256, 256, 0, stream>>>(w0, w1, w2, wT);
        iwht_kernel<true><<<NBLOCKS, 256, 0, stream>>>(x0, x1, x2, w0, w1, w2, wT,
                                                       b0, b1, b2, out);
    } else {
        iwht_kernel<false><<<NBLOCKS, 256, 0, stream>>>(x0, x1, x2, w0, w1, w2, wT,
                                                        b0, b1, b2, out);
    }
}